// Round 6
// baseline (388.878 us; speedup 1.0000x reference)
//
#include <hip/hip_runtime.h>
#include <hip/hip_bf16.h>
#include <math.h>

#define LOSS_WEIGHT 0.1f

typedef unsigned short u16;
typedef __bf16 bf16x8 __attribute__((ext_vector_type(8)));
typedef float f32x4 __attribute__((ext_vector_type(4)));

// ---- global -> LDS direct copy, 16B per lane ----
__device__ __forceinline__ void gload_lds16(const void* gsrc, void* ldst) {
    const __attribute__((address_space(1))) unsigned int* g =
        reinterpret_cast<const __attribute__((address_space(1))) unsigned int*>(
            reinterpret_cast<uintptr_t>(gsrc));
    __attribute__((address_space(3))) unsigned int* l =
        reinterpret_cast<__attribute__((address_space(3))) unsigned int*>(
            reinterpret_cast<uintptr_t>(ldst));
    __builtin_amdgcn_global_load_lds(g, l, 16, 0, 0);
}

__device__ __forceinline__ u16 f2b(float f) {
    __bf16 b = (__bf16)f;
    return __builtin_bit_cast(u16, b);
}
__device__ __forceinline__ unsigned pack2(float a, float b) {
    return (unsigned)f2b(a) | ((unsigned)f2b(b) << 16);
}

// ---- gather: compact indices of tokens with tti==1 ----
__global__ __launch_bounds__(256) void gather_kernel(
    const int* __restrict__ tti, int* __restrict__ idx_list,
    int* __restrict__ count, int N)
{
    int n = blockIdx.x * blockDim.x + threadIdx.x;
    if (n < N && tti[n] == 1) {
        int pos = atomicAdd(count, 1);
        idx_list[pos] = n;
    }
}

// ---- prep: fat grid-stride, one WAVE per row ----
// row space: [0, cntp): gathered tokens (x,t -> xb,tb + t_sq; zero-pad tail)
//            [cntp, cntp+K): W rows.  [cntp+K, cntp+2K): C rows (+c_sq).
__global__ __launch_bounds__(256) void prep_kernel(
    const float* __restrict__ x, const float* __restrict__ t,
    const float* __restrict__ W, const float* __restrict__ C,
    const int* __restrict__ idx_list, const int* __restrict__ count,
    u16* __restrict__ xb, u16* __restrict__ tb,
    u16* __restrict__ wb, u16* __restrict__ cb,
    float* __restrict__ t_sq, float* __restrict__ c_sq,
    int K, int H, int total_waves)
{
    const int lane = threadIdx.x & 63;
    const int wv   = threadIdx.x >> 6;
    const int gw   = blockIdx.x * 4 + wv;
    const int cnt  = *count;
    const int cntp = (cnt + 127) & ~127;
    const int R    = cntp + 2 * K;

    for (int r = gw; r < R; r += total_waves) {
        if (r < cntp) {
            u16* ox = xb + (size_t)r * H;
            u16* ot = tb + (size_t)r * H;
            if (r >= cnt) {
                for (int p = lane * 8; p < H; p += 512) {
                    *(uint4*)(ox + p) = (uint4){0u, 0u, 0u, 0u};
                    *(uint4*)(ot + p) = (uint4){0u, 0u, 0u, 0u};
                }
                if (lane == 0) t_sq[r] = 0.f;
                continue;
            }
            const int sr = idx_list[r];
            const float* rx = x + (size_t)sr * H;
            const float* rt = t + (size_t)sr * H;
            float acc = 0.f;
            for (int p = lane * 8; p < H; p += 512) {
                float4 xa  = *(const float4*)(rx + p);
                float4 xbv = *(const float4*)(rx + p + 4);
                float4 ta  = *(const float4*)(rt + p);
                float4 tbv = *(const float4*)(rt + p + 4);
                acc += ta.x*ta.x + ta.y*ta.y + ta.z*ta.z + ta.w*ta.w
                     + tbv.x*tbv.x + tbv.y*tbv.y + tbv.z*tbv.z + tbv.w*tbv.w;
                uint4 px = {pack2(xa.x, xa.y), pack2(xa.z, xa.w),
                            pack2(xbv.x, xbv.y), pack2(xbv.z, xbv.w)};
                uint4 pt = {pack2(ta.x, ta.y), pack2(ta.z, ta.w),
                            pack2(tbv.x, tbv.y), pack2(tbv.z, tbv.w)};
                *(uint4*)(ox + p) = px;
                *(uint4*)(ot + p) = pt;
            }
            #pragma unroll
            for (int s = 1; s < 64; s <<= 1) acc += __shfl_xor(acc, s);
            if (lane == 0) t_sq[r] = acc;
        } else {
            const int q = r - cntp;
            const float* src; u16* dst; float* sq = nullptr; int row;
            if (q < K) { src = W; dst = wb; row = q; }
            else       { src = C; dst = cb; row = q - K; sq = c_sq; }

            const float* rp = src + (size_t)row * H;
            u16* o = dst + (size_t)row * H;
            float acc = 0.f;
            for (int p = lane * 8; p < H; p += 512) {
                float4 a = *(const float4*)(rp + p);
                float4 b = *(const float4*)(rp + p + 4);
                acc += a.x*a.x + a.y*a.y + a.z*a.z + a.w*a.w
                     + b.x*b.x + b.y*b.y + b.z*b.z + b.w*b.w;
                uint4 pk = {pack2(a.x, a.y), pack2(a.z, a.w),
                            pack2(b.x, b.y), pack2(b.z, b.w)};
                *(uint4*)(o + p) = pk;
            }
            if (sq) {
                #pragma unroll
                for (int s = 1; s < 64; s <<= 1) acc += __shfl_xor(acc, s);
                if (lane == 0) sq[row] = acc;
            }
        }
    }
}

// ---- fused dual-GEMM + per-half-tile online-softmax partials ----
// block: 256 thr (4 waves, 2x2). tile: BM=128 tokens x BN=128 codebook, BK=64.
// wave (wr,wc) owns a 64x64 sub-tile of each output: 4x4 fragments of 16x16.
__global__ __launch_bounds__(256, 2) void fused_gemm_kernel(
    const u16* __restrict__ xb, const u16* __restrict__ tb,
    const u16* __restrict__ wb, const u16* __restrict__ cb,
    const float* __restrict__ b_proj, const float* __restrict__ t_sq,
    const float* __restrict__ c_sq, const int* __restrict__ count,
    float* __restrict__ pm, float* __restrict__ ps, float* __restrict__ pw,
    int H, float invD)
{
    const int mb = blockIdx.y;
    const int m0 = mb * 128;
    {
        const int cnt = *count;
        if (m0 >= ((cnt + 127) & ~127)) return;
    }

    __shared__ u16 xs[128 * 64];
    __shared__ u16 ts[128 * 64];
    __shared__ u16 ws[128 * 64];
    __shared__ u16 cs[128 * 64];

    const int tid  = threadIdx.x;
    const int lane = tid & 63;
    const int wv   = tid >> 6;
    const int wr   = wv >> 1;          // row half (0/1)
    const int wc   = wv & 1;           // col half (0/1)
    const int kb   = blockIdx.x;
    const int KB2  = gridDim.x * 2;
    const int k0   = kb * 128;

    f32x4 accL[16], accC[16];
    #pragma unroll
    for (int i = 0; i < 16; ++i) {
        accL[i] = (f32x4){0.f, 0.f, 0.f, 0.f};
        accC[i] = (f32x4){0.f, 0.f, 0.f, 0.f};
    }

    // swizzled ds_read offsets: row stride 128B; XOR byte bits 4-6 with row&7
    const int kx    = (lane & 7) << 4;
    const int koff0 = (((lane >> 4) << 4)) ^ kx;
    const int koff1 = (64 + ((lane >> 4) << 4)) ^ kx;
    const char* xs_b = (const char*)xs + (wr * 64 + (lane & 15)) * 128;
    const char* ts_b = (const char*)ts + (wr * 64 + (lane & 15)) * 128;
    const char* ws_b = (const char*)ws + (wc * 64 + (lane & 15)) * 128;
    const char* cs_b = (const char*)cs + (wc * 64 + (lane & 15)) * 128;

    const int e0 = tid * 8;

    for (int h0 = 0; h0 < H; h0 += 64) {
        #pragma unroll
        for (int j = 0; j < 4; ++j) {
            int el  = j * 2048 + e0;
            int es  = el ^ (((el >> 6) & 7) << 3);
            int row = es >> 6, col = es & 63;
            gload_lds16(xb + (size_t)(m0 + row) * H + h0 + col, (u16*)xs + el);
            gload_lds16(tb + (size_t)(m0 + row) * H + h0 + col, (u16*)ts + el);
            gload_lds16(wb + (size_t)(k0 + row) * H + h0 + col, (u16*)ws + el);
            gload_lds16(cb + (size_t)(k0 + row) * H + h0 + col, (u16*)cs + el);
        }
        __syncthreads();

        #pragma unroll
        for (int kk = 0; kk < 2; ++kk) {
            const int ko = kk ? koff1 : koff0;
            bf16x8 ax[4], at[4], bw[4], bc[4];
            #pragma unroll
            for (int i = 0; i < 4; ++i) {
                ax[i] = *(const bf16x8*)(xs_b + i * 2048 + ko);
                at[i] = *(const bf16x8*)(ts_b + i * 2048 + ko);
                bw[i] = *(const bf16x8*)(ws_b + i * 2048 + ko);
                bc[i] = *(const bf16x8*)(cs_b + i * 2048 + ko);
            }
            #pragma unroll
            for (int mi = 0; mi < 4; ++mi) {
                #pragma unroll
                for (int ni = 0; ni < 4; ++ni) {
                    accL[mi * 4 + ni] = __builtin_amdgcn_mfma_f32_16x16x32_bf16(
                        ax[mi], bw[ni], accL[mi * 4 + ni], 0, 0, 0);
                    accC[mi * 4 + ni] = __builtin_amdgcn_mfma_f32_16x16x32_bf16(
                        at[mi], bc[ni], accC[mi * 4 + ni], 0, 0, 0);
                }
            }
        }
        __syncthreads();
    }

    // epilogue: C/D layout col = lane&15 (+16*ni), row = (lane>>4)*4 + j (+16*mi)
    float bias[4], csq[4];
    #pragma unroll
    for (int ni = 0; ni < 4; ++ni) {
        int c = k0 + wc * 64 + ni * 16 + (lane & 15);
        bias[ni] = b_proj[c];
        csq[ni]  = c_sq[c];
    }
    const int rbase = m0 + wr * 64 + ((lane >> 4) << 2);
    #pragma unroll
    for (int mi = 0; mi < 4; ++mi) {
        #pragma unroll
        for (int j = 0; j < 4; ++j) {
            const int row = rbase + mi * 16 + j;
            const float tsq = t_sq[row];
            float lg[4], ms[4];
            float mx = -1e30f;
            #pragma unroll
            for (int ni = 0; ni < 4; ++ni) {
                lg[ni] = accL[mi * 4 + ni][j] + bias[ni];
                ms[ni] = (tsq - 2.f * accC[mi * 4 + ni][j] + csq[ni]) * invD;
                mx = fmaxf(mx, lg[ni]);
            }
            #pragma unroll
            for (int s = 1; s < 16; s <<= 1) mx = fmaxf(mx, __shfl_xor(mx, s));
            float esum = 0.f, wsum = 0.f;
            #pragma unroll
            for (int ni = 0; ni < 4; ++ni) {
                float e = __expf(lg[ni] - mx);
                esum += e;
                wsum += e * ms[ni];
            }
            #pragma unroll
            for (int s = 1; s < 16; s <<= 1) {
                esum += __shfl_xor(esum, s);
                wsum += __shfl_xor(wsum, s);
            }
            if ((lane & 15) == 0) {
                size_t idx = (size_t)row * KB2 + kb * 2 + wc;
                pm[idx] = mx; ps[idx] = esum; pw[idx] = wsum;
            }
        }
    }
}

// ---- finalize: merge per-half-tile partials per compacted token ----
__global__ __launch_bounds__(256) void finalize_kernel(
    const float* __restrict__ pm, const float* __restrict__ ps,
    const float* __restrict__ pw, const int* __restrict__ count,
    float* __restrict__ out, int KB2)
{
    const int lane = threadIdx.x & 63;
    const int wv   = threadIdx.x >> 6;
    const int tok  = blockIdx.x * 4 + wv;
    const int cnt  = *count;
    float contrib = 0.f;
    if (tok < cnt) {
        const size_t base = (size_t)tok * KB2;
        float m = -1e30f;
        for (int i = lane; i < KB2; i += 64) m = fmaxf(m, pm[base + i]);
        #pragma unroll
        for (int s = 1; s < 64; s <<= 1) m = fmaxf(m, __shfl_xor(m, s));
        float esum = 0.f, wsum = 0.f;
        for (int i = lane; i < KB2; i += 64) {
            float sc = __expf(pm[base + i] - m);
            esum += ps[base + i] * sc;
            wsum += pw[base + i] * sc;
        }
        #pragma unroll
        for (int s = 1; s < 64; s <<= 1) {
            esum += __shfl_xor(esum, s);
            wsum += __shfl_xor(wsum, s);
        }
        contrib = wsum / esum;
    }
    __shared__ float bsum[4];
    if (lane == 0) bsum[wv] = contrib;
    __syncthreads();
    if (threadIdx.x == 0) {
        float v = (bsum[0] + bsum[1] + bsum[2] + bsum[3]) * LOSS_WEIGHT;
        atomicAdd(out, v);
    }
}

extern "C" void kernel_launch(void* const* d_in, const int* in_sizes, int n_in,
                              void* d_out, int out_size, void* d_ws, size_t ws_size,
                              hipStream_t stream)
{
    const float* x   = (const float*)d_in[0];
    const int*   tti = (const int*)d_in[1];
    const float* t   = (const float*)d_in[2];
    const float* W   = (const float*)d_in[3];
    const float* b   = (const float*)d_in[4];
    const float* C   = (const float*)d_in[5];

    const int N   = in_sizes[1];           // B*S = 4096
    const int K   = in_sizes[4];           // 16384
    const int H   = in_sizes[0] / N;       // 1024
    const int KB2 = K / 64;                // partial slots per token

    char* p = (char*)d_ws;
    auto alloc = [&](size_t bytes) {
        char* r = p;
        p += (bytes + 255) & ~(size_t)255;
        return r;
    };
    u16*   xb   = (u16*)alloc((size_t)N * H * 2);
    u16*   tb   = (u16*)alloc((size_t)N * H * 2);
    u16*   wb   = (u16*)alloc((size_t)K * H * 2);
    u16*   cb   = (u16*)alloc((size_t)K * H * 2);
    float* t_sq = (float*)alloc((size_t)N * 4);
    float* c_sq = (float*)alloc((size_t)K * 4);
    float* pm   = (float*)alloc((size_t)N * KB2 * 4);
    float* ps   = (float*)alloc((size_t)N * KB2 * 4);
    float* pw   = (float*)alloc((size_t)N * KB2 * 4);
    int*   ilist= (int*)alloc((size_t)N * 4);
    int*   cnt  = (int*)alloc(4);

    hipMemsetAsync(d_out, 0, sizeof(float), stream);
    hipMemsetAsync(cnt, 0, sizeof(int), stream);

    gather_kernel<<<(N + 255) / 256, 256, 0, stream>>>(tti, ilist, cnt, N);

    const int PREP_BLOCKS = 2048;
    prep_kernel<<<PREP_BLOCKS, 256, 0, stream>>>(
        x, t, W, C, ilist, cnt, xb, tb, wb, cb, t_sq, c_sq,
        K, H, PREP_BLOCKS * 4);

    dim3 grid(K / 128, N / 128);
    fused_gemm_kernel<<<grid, 256, 0, stream>>>(
        xb, tb, wb, cb, b, t_sq, c_sq, cnt, pm, ps, pw, H, 1.f / (float)H);

    finalize_kernel<<<(N + 3) / 4, 256, 0, stream>>>(
        pm, ps, pw, cnt, (float*)d_out, KB2);
}